// Round 1
// baseline (449.890 us; speedup 1.0000x reference)
//
#include <hip/hip_runtime.h>
#include <stdint.h>

// Triangle multiplicative update (outgoing), N=512, CZ=CH=128.
// Stage A: a/b = mask * sigmoid(z@Wg^T + bg) * (z@Wp^T + bp), stored bf16 as
//          planes [c][i*N+k] in d_ws.
// Stage B: out[c,i,j] = sum_k a[i,k,c]*b[j,k,c]  -> 128 GEMMs C = A*B^T.

#define NDIM 512
#define CZ   128
#define CH   128
#define NPOS (NDIM * NDIM)  // 262144

typedef __attribute__((ext_vector_type(8))) __bf16 bf16x8;
typedef __attribute__((ext_vector_type(4))) float  f32x4;

__device__ __forceinline__ unsigned short f2bf(float f) {
  unsigned int u = __builtin_bit_cast(unsigned int, f);
  unsigned int r = (u + 0x7fffu + ((u >> 16) & 1u)) >> 16;  // RNE
  return (unsigned short)r;
}

// ---------------------------------------------------------------- kernel 0
// Convert the 4 weight matrices fp32 -> bf16, layout [proj][c][k],
// proj: 0=ag, 1=ap, 2=bg, 3=bp.
__global__ __launch_bounds__(256) void conv_weights(
    const float* __restrict__ wag, const float* __restrict__ wap,
    const float* __restrict__ wbg, const float* __restrict__ wbp,
    unsigned short* __restrict__ wbf) {
  int idx = blockIdx.x * 256 + threadIdx.x;  // 0..65535
  int proj = idx >> 14;
  int rem  = idx & 16383;
  const float* src = (proj == 0) ? wag : (proj == 1) ? wap : (proj == 2) ? wbg : wbp;
  wbf[idx] = f2bf(src[rem]);
}

// ---------------------------------------------------------------- kernel A
// Block: 64 positions x 128 channels, for one of the (gate,lin) pairs.
// 4 waves arranged 2x2; wave tile 32 pos x 64 ch; two accumulator sets.
__global__ __launch_bounds__(256) void proj_fuse(
    const float* __restrict__ z,            // [NPOS][CZ]
    const float* __restrict__ mask,         // [NPOS]
    const unsigned short* __restrict__ wbf, // [4][CH][CZ] bf16
    const float* __restrict__ bias_ag, const float* __restrict__ bias_ap,
    const float* __restrict__ bias_bg, const float* __restrict__ bias_bp,
    unsigned short* __restrict__ a_ws,      // [CH][NPOS] bf16
    unsigned short* __restrict__ b_ws) {
  __shared__ unsigned short sbuf[128 * 72];  // 18432 B; reused: Z tile then transpose

  const int t    = threadIdx.x;
  const int lane = t & 63;
  const int wave = t >> 6;
  const int wm   = wave >> 1;  // 0..1 (pos half)
  const int wn   = wave & 1;   // 0..1 (channel half)
  const int m0   = blockIdx.x * 64;  // position tile base
  const int pair = blockIdx.y;       // 0 -> a (ag,ap), 1 -> b (bg,bp)

  // ---- stage Z tile [64 pos][128 cz] fp32 -> bf16 into LDS (stride 136 shorts)
  {
    const int col4  = t & 31;  // float4 index in row
    const int rbase = t >> 5;  // 0..7
    for (int it = 0; it < 8; ++it) {
      const int row = it * 8 + rbase;
      const float4 v = *(const float4*)(z + (size_t)(m0 + row) * CZ + col4 * 4);
      unsigned int lo = (unsigned int)f2bf(v.x) | ((unsigned int)f2bf(v.y) << 16);
      unsigned int hi = (unsigned int)f2bf(v.z) | ((unsigned int)f2bf(v.w) << 16);
      *(uint2*)&sbuf[row * 136 + col4 * 4] = make_uint2(lo, hi);
    }
  }
  __syncthreads();

  const int pg = pair * 2;      // gate proj index
  const int pp = pg + 1;        // linear proj index

  f32x4 accg[2][4], accp[2][4];
  for (int mi = 0; mi < 2; ++mi)
    for (int ni = 0; ni < 4; ++ni) {
      accg[mi][ni] = (f32x4){0.f, 0.f, 0.f, 0.f};
      accp[mi][ni] = (f32x4){0.f, 0.f, 0.f, 0.f};
    }

  const int mrow  = wm * 32 + (lane & 15);       // + mi*16
  const int nrow  = wn * 64 + (lane & 15);       // + ni*16  (channel)
  const int koffl = (lane >> 4) * 8;             // shorts

  for (int ks = 0; ks < 4; ++ks) {
    bf16x8 af[2];
    af[0] = *(const bf16x8*)&sbuf[(mrow)      * 136 + ks * 32 + koffl];
    af[1] = *(const bf16x8*)&sbuf[(mrow + 16) * 136 + ks * 32 + koffl];
#pragma unroll
    for (int ni = 0; ni < 4; ++ni) {
      const int c = nrow + ni * 16;
      bf16x8 bg = *(const bf16x8*)&wbf[(pg * CH + c) * CZ + ks * 32 + koffl];
      bf16x8 bp = *(const bf16x8*)&wbf[(pp * CH + c) * CZ + ks * 32 + koffl];
      accg[0][ni] = __builtin_amdgcn_mfma_f32_16x16x32_bf16(af[0], bg, accg[0][ni], 0, 0, 0);
      accg[1][ni] = __builtin_amdgcn_mfma_f32_16x16x32_bf16(af[1], bg, accg[1][ni], 0, 0, 0);
      accp[0][ni] = __builtin_amdgcn_mfma_f32_16x16x32_bf16(af[0], bp, accp[0][ni], 0, 0, 0);
      accp[1][ni] = __builtin_amdgcn_mfma_f32_16x16x32_bf16(af[1], bp, accp[1][ni], 0, 0, 0);
    }
  }
  __syncthreads();  // all waves done reading Z tile before reuse

  // ---- fused epilogue: val = mask * sigmoid(g + bg) * (p + bp), bf16
  const float* bgp = pair ? bias_bg : bias_ag;
  const float* bpp = pair ? bias_bp : bias_ap;

  float mk[2][4];
  for (int mi = 0; mi < 2; ++mi)
    for (int r = 0; r < 4; ++r)
      mk[mi][r] = mask[m0 + wm * 32 + mi * 16 + (lane >> 4) * 4 + r];

#pragma unroll
  for (int ni = 0; ni < 4; ++ni) {
    const int c = nrow + ni * 16;
    const float bgv = bgp[c];
    const float bpv = bpp[c];
#pragma unroll
    for (int mi = 0; mi < 2; ++mi) {
      unsigned short h[4];
#pragma unroll
      for (int r = 0; r < 4; ++r) {
        float g = accg[mi][ni][r] + bgv;
        float p = accp[mi][ni][r] + bpv;
        float s = 1.0f / (1.0f + __expf(-g));
        h[r] = f2bf(mk[mi][r] * s * p);
      }
      const int mloc = wm * 32 + mi * 16 + (lane >> 4) * 4;
      // transpose buffer: [c][pos], stride 72 shorts
      *(uint2*)&sbuf[c * 72 + mloc] =
          make_uint2((unsigned int)h[0] | ((unsigned int)h[1] << 16),
                     (unsigned int)h[2] | ((unsigned int)h[3] << 16));
    }
  }
  __syncthreads();

  // ---- coalesced store of the [128 ch][64 pos] tile to plane [c][p]
  unsigned short* plane = pair ? b_ws : a_ws;
  {
    const int p4 = t & 15;   // 4-short chunk in pos dim
    const int cb = t >> 4;   // 0..15
    for (int it = 0; it < 8; ++it) {
      const int c = it * 16 + cb;
      uint2 v = *(const uint2*)&sbuf[c * 72 + p4 * 4];
      *(uint2*)(plane + (size_t)c * NPOS + m0 + p4 * 4) = v;
    }
  }
}

// ---------------------------------------------------------------- kernel B
// Per-channel GEMM out[c] = A_c * B_c^T, A/B bf16 [512][512], m97-style:
// 128x128 block tile, BK=32, global_load_lds width-16 staging.
__global__ __launch_bounds__(256) void tri_gemm(
    const unsigned short* __restrict__ a_ws,
    const unsigned short* __restrict__ b_ws,
    float* __restrict__ out) {
  __shared__ unsigned short sA[128 * 32];
  __shared__ unsigned short sB[128 * 32];

  const int t = threadIdx.x, lane = t & 63, wave = t >> 6;
  const int wm = wave >> 1, wn = wave & 1;
  const int tj = blockIdx.x, ti = blockIdx.y, c = blockIdx.z;
  const int i0 = ti * 128, j0 = tj * 128;

  const unsigned short* Ap = a_ws + (size_t)c * NPOS + (size_t)i0 * NDIM;
  const unsigned short* Bp = b_ws + (size_t)c * NPOS + (size_t)j0 * NDIM;

  f32x4 acc[4][4];
  for (int mi = 0; mi < 4; ++mi)
    for (int ni = 0; ni < 4; ++ni) acc[mi][ni] = (f32x4){0.f, 0.f, 0.f, 0.f};

  const int srow  = t >> 2;            // 0..63 staging row
  const int scol  = t & 3;             // 16B chunk in 64B row
  const int mrow  = wm * 64 + (lane & 15);
  const int nrow  = wn * 64 + (lane & 15);
  const int koffl = (lane >> 4) * 8;

  for (int kk = 0; kk < 16; ++kk) {
    const int k0 = kk * 32;  // shorts
    __builtin_amdgcn_global_load_lds(
        (const __attribute__((address_space(1))) unsigned int*)(Ap + (size_t)srow * NDIM + k0 + scol * 8),
        (__attribute__((address_space(3))) unsigned int*)&sA[t * 8], 16, 0, 0);
    __builtin_amdgcn_global_load_lds(
        (const __attribute__((address_space(1))) unsigned int*)(Ap + (size_t)(srow + 64) * NDIM + k0 + scol * 8),
        (__attribute__((address_space(3))) unsigned int*)&sA[2048 + t * 8], 16, 0, 0);
    __builtin_amdgcn_global_load_lds(
        (const __attribute__((address_space(1))) unsigned int*)(Bp + (size_t)srow * NDIM + k0 + scol * 8),
        (__attribute__((address_space(3))) unsigned int*)&sB[t * 8], 16, 0, 0);
    __builtin_amdgcn_global_load_lds(
        (const __attribute__((address_space(1))) unsigned int*)(Bp + (size_t)(srow + 64) * NDIM + k0 + scol * 8),
        (__attribute__((address_space(3))) unsigned int*)&sB[2048 + t * 8], 16, 0, 0);
    __syncthreads();

    bf16x8 af[4], bfr[4];
#pragma unroll
    for (int mi = 0; mi < 4; ++mi)
      af[mi] = *(const bf16x8*)&sA[(mrow + mi * 16) * 32 + koffl];
#pragma unroll
    for (int ni = 0; ni < 4; ++ni)
      bfr[ni] = *(const bf16x8*)&sB[(nrow + ni * 16) * 32 + koffl];
#pragma unroll
    for (int mi = 0; mi < 4; ++mi)
#pragma unroll
      for (int ni = 0; ni < 4; ++ni)
        acc[mi][ni] = __builtin_amdgcn_mfma_f32_16x16x32_bf16(af[mi], bfr[ni], acc[mi][ni], 0, 0, 0);
    __syncthreads();
  }

  float* O = out + (size_t)c * NPOS + (size_t)i0 * NDIM + j0;
#pragma unroll
  for (int mi = 0; mi < 4; ++mi)
#pragma unroll
    for (int r = 0; r < 4; ++r) {
      const int m = wm * 64 + mi * 16 + (lane >> 4) * 4 + r;
#pragma unroll
      for (int ni = 0; ni < 4; ++ni) {
        const int n = wn * 64 + ni * 16 + (lane & 15);
        O[(size_t)m * NDIM + n] = acc[mi][ni][r];
      }
    }
}

// ---------------------------------------------------------------- launcher
extern "C" void kernel_launch(void* const* d_in, const int* in_sizes, int n_in,
                              void* d_out, int out_size, void* d_ws, size_t ws_size,
                              hipStream_t stream) {
  const float* z    = (const float*)d_in[0];
  const float* mask = (const float*)d_in[1];
  const float* wag  = (const float*)d_in[2];
  const float* bag  = (const float*)d_in[3];
  const float* wap  = (const float*)d_in[4];
  const float* bap  = (const float*)d_in[5];
  const float* wbg  = (const float*)d_in[6];
  const float* bbg  = (const float*)d_in[7];
  const float* wbp  = (const float*)d_in[8];
  const float* bbp  = (const float*)d_in[9];
  float* out = (float*)d_out;

  unsigned short* wbf  = (unsigned short*)d_ws;
  unsigned short* a_ws = (unsigned short*)((char*)d_ws + 131072);
  unsigned short* b_ws = (unsigned short*)((char*)d_ws + 131072 + (size_t)CH * NPOS * 2);

  conv_weights<<<dim3(256), dim3(256), 0, stream>>>(wag, wap, wbg, wbp, wbf);
  proj_fuse<<<dim3(NPOS / 64, 2), dim3(256), 0, stream>>>(
      z, mask, wbf, bag, bap, bbg, bbp, a_ws, b_ws);
  tri_gemm<<<dim3(4, 4, CH), dim3(256), 0, stream>>>(a_ws, b_ws, out);
}

// Round 2
// 435.001 us; speedup vs baseline: 1.0342x; 1.0342x over previous
//
#include <hip/hip_runtime.h>
#include <stdint.h>

// Triangle multiplicative update (outgoing), N=512, CZ=CH=128.
// Stage A: a/b = mask * sigmoid(z@Wg^T + bg) * (z@Wp^T + bp), stored bf16 as
//          planes [c][i*N+k] in d_ws.
// Stage B: out[c,i,j] = sum_k a[i,k,c]*b[j,k,c]  -> 128 GEMMs C = A*B^T.

#define NDIM 512
#define CZ   128
#define CH   128
#define NPOS (NDIM * NDIM)  // 262144
#define TILES 4             // pos-tiles of 64 per proj_fuse block

typedef __attribute__((ext_vector_type(8))) __bf16 bf16x8;
typedef __attribute__((ext_vector_type(4))) float  f32x4;

__device__ __forceinline__ unsigned short f2bf(float f) {
  unsigned int u = __builtin_bit_cast(unsigned int, f);
  unsigned int r = (u + 0x7fffu + ((u >> 16) & 1u)) >> 16;  // RNE
  return (unsigned short)r;
}

// ---------------------------------------------------------------- kernel 0
// fp32 -> bf16 weights, layout [proj][c][k], proj: 0=ag,1=ap,2=bg,3=bp.
__global__ __launch_bounds__(256) void conv_weights(
    const float* __restrict__ wag, const float* __restrict__ wap,
    const float* __restrict__ wbg, const float* __restrict__ wbp,
    unsigned short* __restrict__ wbf) {
  int idx = blockIdx.x * 256 + threadIdx.x;  // 0..65535
  int proj = idx >> 14;
  int rem  = idx & 16383;
  const float* src = (proj == 0) ? wag : (proj == 1) ? wap : (proj == 2) ? wbg : wbp;
  wbf[idx] = f2bf(src[rem]);
}

// ---------------------------------------------------------------- kernel A
// Block: TILES x (64 pos) x 128 ch for one (gate,lin) pair.
// Weight fragments hoisted to registers (loop-invariant, 128 VGPR).
// z tile prefetched into VGPRs while previous tile's MFMA runs.
__global__ __launch_bounds__(256, 2) void proj_fuse(
    const float* __restrict__ z,            // [NPOS][CZ]
    const float* __restrict__ mask,         // [NPOS]
    const unsigned short* __restrict__ wbf, // [4][CH][CZ] bf16
    const float* __restrict__ bias_ag, const float* __restrict__ bias_ap,
    const float* __restrict__ bias_bg, const float* __restrict__ bias_bp,
    unsigned short* __restrict__ a_ws,      // [CH][NPOS] bf16
    unsigned short* __restrict__ b_ws) {
  __shared__ unsigned short zbuf[64 * 136];   // z tile, bf16, padded stride
  __shared__ unsigned short tbuf[128 * 72];   // output transpose buffer

  const int t    = threadIdx.x;
  const int lane = t & 63;
  const int wave = t >> 6;
  const int wm   = wave >> 1;  // pos half
  const int wn   = wave & 1;   // channel half
  const int pair = blockIdx.y; // 0 -> a (ag,ap), 1 -> b (bg,bp)
  const int pg   = pair * 2, pp = pg + 1;

  const int mrow  = wm * 32 + (lane & 15);
  const int nrow  = wn * 64 + (lane & 15);
  const int koffl = (lane >> 4) * 8;

  // ---- hoist all weight fragments into registers (L2-hot, once per block)
  bf16x8 wg[4][4], wp[4][4];
#pragma unroll
  for (int ks = 0; ks < 4; ++ks)
#pragma unroll
    for (int ni = 0; ni < 4; ++ni) {
      const int c = nrow + ni * 16;
      wg[ks][ni] = *(const bf16x8*)&wbf[(pg * CH + c) * CZ + ks * 32 + koffl];
      wp[ks][ni] = *(const bf16x8*)&wbf[(pp * CH + c) * CZ + ks * 32 + koffl];
    }

  const float* bgp = pair ? bias_bg : bias_ag;
  const float* bpp = pair ? bias_bp : bias_ap;
  unsigned short* plane = pair ? b_ws : a_ws;

  const int col4  = t & 31;  // float4 index in z row
  const int rbase = t >> 5;  // 0..7

  const int m0 = blockIdx.x * (TILES * 64);

  // prefetch tile 0 into registers
  float4 zf[8];
#pragma unroll
  for (int it = 0; it < 8; ++it)
    zf[it] = *(const float4*)(z + (size_t)(m0 + it * 8 + rbase) * CZ + col4 * 4);

  for (int tt = 0; tt < TILES; ++tt) {
    const int mt = m0 + tt * 64;

    // ---- convert + write prefetched z tile to LDS
#pragma unroll
    for (int it = 0; it < 8; ++it) {
      const int row = it * 8 + rbase;
      unsigned int lo = (unsigned int)f2bf(zf[it].x) | ((unsigned int)f2bf(zf[it].y) << 16);
      unsigned int hi = (unsigned int)f2bf(zf[it].z) | ((unsigned int)f2bf(zf[it].w) << 16);
      *(uint2*)&zbuf[row * 136 + col4 * 4] = make_uint2(lo, hi);
    }
    __syncthreads();

    // ---- prefetch next z tile (in flight across MFMA + epilogue)
    if (tt + 1 < TILES) {
#pragma unroll
      for (int it = 0; it < 8; ++it)
        zf[it] = *(const float4*)(z + (size_t)(mt + 64 + it * 8 + rbase) * CZ + col4 * 4);
    }
    // mask values for this tile's epilogue
    float mk[2][4];
#pragma unroll
    for (int mi = 0; mi < 2; ++mi)
#pragma unroll
      for (int r = 0; r < 4; ++r)
        mk[mi][r] = mask[mt + wm * 32 + mi * 16 + (lane >> 4) * 4 + r];

    // ---- MFMA (LDS + registers only)
    f32x4 accg[2][4], accp[2][4];
#pragma unroll
    for (int mi = 0; mi < 2; ++mi)
#pragma unroll
      for (int ni = 0; ni < 4; ++ni) {
        accg[mi][ni] = (f32x4){0.f, 0.f, 0.f, 0.f};
        accp[mi][ni] = (f32x4){0.f, 0.f, 0.f, 0.f};
      }
#pragma unroll
    for (int ks = 0; ks < 4; ++ks) {
      bf16x8 af0 = *(const bf16x8*)&zbuf[(mrow)      * 136 + ks * 32 + koffl];
      bf16x8 af1 = *(const bf16x8*)&zbuf[(mrow + 16) * 136 + ks * 32 + koffl];
#pragma unroll
      for (int ni = 0; ni < 4; ++ni) {
        accg[0][ni] = __builtin_amdgcn_mfma_f32_16x16x32_bf16(af0, wg[ks][ni], accg[0][ni], 0, 0, 0);
        accg[1][ni] = __builtin_amdgcn_mfma_f32_16x16x32_bf16(af1, wg[ks][ni], accg[1][ni], 0, 0, 0);
        accp[0][ni] = __builtin_amdgcn_mfma_f32_16x16x32_bf16(af0, wp[ks][ni], accp[0][ni], 0, 0, 0);
        accp[1][ni] = __builtin_amdgcn_mfma_f32_16x16x32_bf16(af1, wp[ks][ni], accp[1][ni], 0, 0, 0);
      }
    }

    // ---- fused epilogue into transpose buffer [c][pos]
#pragma unroll
    for (int ni = 0; ni < 4; ++ni) {
      const int c = nrow + ni * 16;
      const float bgv = bgp[c];
      const float bpv = bpp[c];
#pragma unroll
      for (int mi = 0; mi < 2; ++mi) {
        unsigned short h[4];
#pragma unroll
        for (int r = 0; r < 4; ++r) {
          float g = accg[mi][ni][r] + bgv;
          float p = accp[mi][ni][r] + bpv;
          float s = 1.0f / (1.0f + __expf(-g));
          h[r] = f2bf(mk[mi][r] * s * p);
        }
        const int mloc = wm * 32 + mi * 16 + (lane >> 4) * 4;
        *(uint2*)&tbuf[c * 72 + mloc] =
            make_uint2((unsigned int)h[0] | ((unsigned int)h[1] << 16),
                       (unsigned int)h[2] | ((unsigned int)h[3] << 16));
      }
    }
    __syncthreads();

    // ---- coalesced store of [128 ch][64 pos] tile to plane [c][pos]
    {
      const int p4 = t & 15;
      const int cb = t >> 4;
#pragma unroll
      for (int it = 0; it < 8; ++it) {
        const int c = it * 16 + cb;
        uint2 v = *(const uint2*)&tbuf[c * 72 + p4 * 4];
        *(uint2*)(plane + (size_t)c * NPOS + mt + p4 * 4) = v;
      }
    }
  }
}

// ---------------------------------------------------------------- kernel B
// Per-channel GEMM out[c] = A_c * B_c^T, bf16 [512][512].
// 128x128 tile, BK=64, global_load_lds width-16, XOR-swizzled LDS chunks
// so ds_read_b128 fragment reads are bank-conflict-free.
__global__ __launch_bounds__(256, 3) void tri_gemm(
    const unsigned short* __restrict__ a_ws,
    const unsigned short* __restrict__ b_ws,
    float* __restrict__ out) {
  __shared__ unsigned short sA[128 * 64];  // 16 KB, rows of 64 shorts (8 x 16B chunks)
  __shared__ unsigned short sB[128 * 64];

  const int t = threadIdx.x, lane = t & 63, wave = t >> 6;
  const int wm = wave >> 1, wn = wave & 1;
  const int tj = blockIdx.x, ti = blockIdx.y, c = blockIdx.z;
  const int i0 = ti * 128, j0 = tj * 128;

  const unsigned short* Ap = a_ws + (size_t)c * NPOS + (size_t)i0 * NDIM;
  const unsigned short* Bp = b_ws + (size_t)c * NPOS + (size_t)j0 * NDIM;

  f32x4 acc[4][4];
#pragma unroll
  for (int mi = 0; mi < 4; ++mi)
#pragma unroll
    for (int ni = 0; ni < 4; ++ni) acc[mi][ni] = (f32x4){0.f, 0.f, 0.f, 0.f};

  const int srow8  = t >> 3;  // row within a 32-row staging group
  const int schunk = t & 7;   // physical 16B chunk within row
  const int mrow = wm * 64 + (lane & 15);
  const int nrow = wn * 64 + (lane & 15);

  for (int kk = 0; kk < 8; ++kk) {
    const int k0 = kk * 64;  // shorts
#pragma unroll
    for (int i = 0; i < 4; ++i) {
      const int row = i * 32 + srow8;
      const int kcs = schunk ^ (row & 7);  // swizzled source chunk
      __builtin_amdgcn_global_load_lds(
          (const __attribute__((address_space(1))) unsigned int*)(Ap + (size_t)row * NDIM + k0 + kcs * 8),
          (__attribute__((address_space(3))) unsigned int*)&sA[(i * 256 + t) * 8], 16, 0, 0);
      __builtin_amdgcn_global_load_lds(
          (const __attribute__((address_space(1))) unsigned int*)(Bp + (size_t)row * NDIM + k0 + kcs * 8),
          (__attribute__((address_space(3))) unsigned int*)&sB[(i * 256 + t) * 8], 16, 0, 0);
    }
    __syncthreads();

#pragma unroll
    for (int ksub = 0; ksub < 2; ++ksub) {
      const int kc = ksub * 4 + (lane >> 4);  // logical 16B chunk 0..7
      bf16x8 af[4], bfr[4];
#pragma unroll
      for (int mi = 0; mi < 4; ++mi) {
        const int r = mrow + mi * 16;
        af[mi] = *(const bf16x8*)&sA[r * 64 + ((kc ^ (r & 7)) << 3)];
      }
#pragma unroll
      for (int ni = 0; ni < 4; ++ni) {
        const int r = nrow + ni * 16;
        bfr[ni] = *(const bf16x8*)&sB[r * 64 + ((kc ^ (r & 7)) << 3)];
      }
#pragma unroll
      for (int mi = 0; mi < 4; ++mi)
#pragma unroll
        for (int ni = 0; ni < 4; ++ni)
          acc[mi][ni] = __builtin_amdgcn_mfma_f32_16x16x32_bf16(af[mi], bfr[ni], acc[mi][ni], 0, 0, 0);
    }
    __syncthreads();
  }

  float* O = out + (size_t)c * NPOS + (size_t)i0 * NDIM + j0;
#pragma unroll
  for (int mi = 0; mi < 4; ++mi)
#pragma unroll
    for (int r = 0; r < 4; ++r) {
      const int m = wm * 64 + mi * 16 + (lane >> 4) * 4 + r;
#pragma unroll
      for (int ni = 0; ni < 4; ++ni) {
        const int n = wn * 64 + ni * 16 + (lane & 15);
        O[(size_t)m * NDIM + n] = acc[mi][ni][r];
      }
    }
}

// ---------------------------------------------------------------- launcher
extern "C" void kernel_launch(void* const* d_in, const int* in_sizes, int n_in,
                              void* d_out, int out_size, void* d_ws, size_t ws_size,
                              hipStream_t stream) {
  const float* z    = (const float*)d_in[0];
  const float* mask = (const float*)d_in[1];
  const float* wag  = (const float*)d_in[2];
  const float* bag  = (const float*)d_in[3];
  const float* wap  = (const float*)d_in[4];
  const float* bap  = (const float*)d_in[5];
  const float* wbg  = (const float*)d_in[6];
  const float* bbg  = (const float*)d_in[7];
  const float* wbp  = (const float*)d_in[8];
  const float* bbp  = (const float*)d_in[9];
  float* out = (float*)d_out;

  unsigned short* wbf  = (unsigned short*)d_ws;
  unsigned short* a_ws = (unsigned short*)((char*)d_ws + 131072);
  unsigned short* b_ws = (unsigned short*)((char*)d_ws + 131072 + (size_t)CH * NPOS * 2);

  conv_weights<<<dim3(256), dim3(256), 0, stream>>>(wag, wap, wbg, wbp, wbf);
  proj_fuse<<<dim3(NPOS / (64 * TILES), 2), dim3(256), 0, stream>>>(
      z, mask, wbf, bag, bap, bbg, bbp, a_ws, b_ws);
  tri_gemm<<<dim3(4, 4, CH), dim3(256), 0, stream>>>(a_ws, b_ws, out);
}

// Round 3
// 433.469 us; speedup vs baseline: 1.0379x; 1.0035x over previous
//
#include <hip/hip_runtime.h>
#include <stdint.h>

// Triangle multiplicative update (outgoing), N=512, CZ=CH=128.
// Stage A (proj_fuse): one pass over z computes all 4 projections
//   (ag,ap,bg,bp); a = mask*sigmoid(zWag+bag)*(zWap+bap), likewise b;
//   stored bf16 as planes [c][pos] in d_ws.
// Stage B (tri_gemm): out[c,i,j] = sum_k a[i,k,c]*b[j,k,c] -> 128 GEMMs.

#define NDIM 512
#define CZ   128
#define CH   128
#define NPOS (NDIM * NDIM)  // 262144

typedef __attribute__((ext_vector_type(8))) __bf16 bf16x8;
typedef __attribute__((ext_vector_type(4))) float  f32x4;

__device__ __forceinline__ unsigned short f2bf(float f) {
  unsigned int u = __builtin_bit_cast(unsigned int, f);
  unsigned int r = (u + 0x7fffu + ((u >> 16) & 1u)) >> 16;  // RNE
  return (unsigned short)r;
}
__device__ __forceinline__ float bf2f_lo(unsigned int u) {
  return __builtin_bit_cast(float, u << 16);
}
__device__ __forceinline__ float bf2f_hi(unsigned int u) {
  return __builtin_bit_cast(float, u & 0xffff0000u);
}

// ---------------------------------------------------------------- kernel 0
// fp32 -> bf16 weights, layout [proj][c][k], proj: 0=ag,1=ap,2=bg,3=bp.
__global__ __launch_bounds__(256) void conv_weights(
    const float* __restrict__ wag, const float* __restrict__ wap,
    const float* __restrict__ wbg, const float* __restrict__ wbp,
    unsigned short* __restrict__ wbf) {
  int idx = blockIdx.x * 256 + threadIdx.x;  // 0..65535
  int proj = idx >> 14;
  int rem  = idx & 16383;
  const float* src = (proj == 0) ? wag : (proj == 1) ? wap : (proj == 2) ? wbg : wbp;
  wbf[idx] = f2bf(src[rem]);
}

// ---------------------------------------------------------------- kernel A
// Block: 32 positions x 128 channels x ALL 4 projections (z read once).
// Wave w computes projection w (acc = 2x8 16x16 tiles = 64 VGPR).
// Gate/lin cross-wave combine through bf16 LDS acc buffer; epilogue uses
// all 256 threads with coalesced [c][pos] plane stores.
__global__ __launch_bounds__(256, 3) void proj_fuse(
    const float* __restrict__ z,            // [NPOS][CZ]
    const float* __restrict__ mask,         // [NPOS]
    const unsigned short* __restrict__ wbf, // [4][CH][CZ] bf16
    const float* __restrict__ bias_ag, const float* __restrict__ bias_ap,
    const float* __restrict__ bias_bg, const float* __restrict__ bias_bp,
    unsigned short* __restrict__ a_ws,      // [CH][NPOS] bf16
    unsigned short* __restrict__ b_ws) {
  __shared__ unsigned short zbuf[32 * 136];      // 8.7 KB, padded stride
  __shared__ unsigned short accb[4 * 128 * 36];  // 36.9 KB, [proj][c][pos] bf16

  const int t    = threadIdx.x;
  const int lane = t & 63;
  const int w    = t >> 6;   // wave id == projection id
  const int m0   = blockIdx.x * 32;

  // ---- stage z tile [32 pos][128 cz] fp32 -> bf16 (read ONCE per block)
  {
    const int c4 = t & 31;   // float4 chunk in row
    const int rb = t >> 5;   // 0..7
#pragma unroll
    for (int it = 0; it < 4; ++it) {
      const int row = it * 8 + rb;
      const float4 v = *(const float4*)(z + (size_t)(m0 + row) * CZ + c4 * 4);
      unsigned int lo = (unsigned int)f2bf(v.x) | ((unsigned int)f2bf(v.y) << 16);
      unsigned int hi = (unsigned int)f2bf(v.z) | ((unsigned int)f2bf(v.w) << 16);
      *(uint2*)&zbuf[row * 136 + c4 * 4] = make_uint2(lo, hi);
    }
  }
  __syncthreads();

  // ---- MFMA: wave w -> projection w over [32 pos][128 ch]
  const int ml    = lane & 15;
  const int q     = lane >> 4;
  const int koffl = q * 8;

  f32x4 acc[2][8];
#pragma unroll
  for (int mi = 0; mi < 2; ++mi)
#pragma unroll
    for (int ni = 0; ni < 8; ++ni) acc[mi][ni] = (f32x4){0.f, 0.f, 0.f, 0.f};

#pragma unroll
  for (int ks = 0; ks < 4; ++ks) {
    bf16x8 af0 = *(const bf16x8*)&zbuf[(ml)      * 136 + ks * 32 + koffl];
    bf16x8 af1 = *(const bf16x8*)&zbuf[(ml + 16) * 136 + ks * 32 + koffl];
#pragma unroll
    for (int ni = 0; ni < 8; ++ni) {
      // weights: 128 KB total, L2-resident; loaded in-loop (no VGPR hoard)
      bf16x8 wf = *(const bf16x8*)&wbf[((size_t)w * CH + ni * 16 + ml) * CZ + ks * 32 + koffl];
      acc[0][ni] = __builtin_amdgcn_mfma_f32_16x16x32_bf16(af0, wf, acc[0][ni], 0, 0, 0);
      acc[1][ni] = __builtin_amdgcn_mfma_f32_16x16x32_bf16(af1, wf, acc[1][ni], 0, 0, 0);
    }
  }

  // ---- write acc (bf16) to accb[w][c][pos]; C-layout: col=ml -> channel,
  //      row = q*4+r (+16*mi) -> position. 8B stores, conflict-free stride 36.
#pragma unroll
  for (int mi = 0; mi < 2; ++mi)
#pragma unroll
    for (int ni = 0; ni < 8; ++ni) {
      const int c    = ni * 16 + ml;
      const int pos0 = mi * 16 + q * 4;
      unsigned int lo = (unsigned int)f2bf(acc[mi][ni][0]) |
                        ((unsigned int)f2bf(acc[mi][ni][1]) << 16);
      unsigned int hi = (unsigned int)f2bf(acc[mi][ni][2]) |
                        ((unsigned int)f2bf(acc[mi][ni][3]) << 16);
      *(uint2*)&accb[((size_t)w * CH + c) * 36 + pos0] = make_uint2(lo, hi);
    }
  __syncthreads();

  // ---- epilogue: all 256 threads; out = mask*sigmoid(g+bg)*(p+bp) -> planes
  const int pc = t & 7;    // pos chunk (4 positions)
  const int cb = t >> 3;   // 0..31 channel base
  const float4 mv = *(const float4*)(mask + m0 + pc * 4);

#pragma unroll
  for (int pair = 0; pair < 2; ++pair) {
    const float* bgp = pair ? bias_bg : bias_ag;
    const float* bpp = pair ? bias_bp : bias_ap;
    unsigned short* plane = pair ? b_ws : a_ws;
    const int pg = pair * 2, pp = pg + 1;
#pragma unroll
    for (int it = 0; it < 4; ++it) {
      const int ch = it * 32 + cb;
      uint2 gv = *(const uint2*)&accb[((size_t)pg * CH + ch) * 36 + pc * 4];
      uint2 pv = *(const uint2*)&accb[((size_t)pp * CH + ch) * 36 + pc * 4];
      const float bg = bgp[ch];
      const float bp = bpp[ch];
      float g[4] = {bf2f_lo(gv.x) + bg, bf2f_hi(gv.x) + bg,
                    bf2f_lo(gv.y) + bg, bf2f_hi(gv.y) + bg};
      float p[4] = {bf2f_lo(pv.x) + bp, bf2f_hi(pv.x) + bp,
                    bf2f_lo(pv.y) + bp, bf2f_hi(pv.y) + bp};
      const float mr[4] = {mv.x, mv.y, mv.z, mv.w};
      unsigned short h[4];
#pragma unroll
      for (int r = 0; r < 4; ++r) {
        float s = 1.0f / (1.0f + __expf(-g[r]));
        h[r] = f2bf(mr[r] * s * p[r]);
      }
      *(uint2*)(plane + (size_t)ch * NPOS + m0 + pc * 4) =
          make_uint2((unsigned int)h[0] | ((unsigned int)h[1] << 16),
                     (unsigned int)h[2] | ((unsigned int)h[3] << 16));
    }
  }
}

// ---------------------------------------------------------------- kernel B
// Per-channel GEMM out[c] = A_c * B_c^T, bf16 [512][512].
// 128x128 tile, BK=64, global_load_lds width-16, XOR-swizzled LDS chunks.
__global__ __launch_bounds__(256, 3) void tri_gemm(
    const unsigned short* __restrict__ a_ws,
    const unsigned short* __restrict__ b_ws,
    float* __restrict__ out) {
  __shared__ unsigned short sA[128 * 64];
  __shared__ unsigned short sB[128 * 64];

  const int t = threadIdx.x, lane = t & 63, wave = t >> 6;
  const int wm = wave >> 1, wn = wave & 1;
  const int tj = blockIdx.x, ti = blockIdx.y, c = blockIdx.z;
  const int i0 = ti * 128, j0 = tj * 128;

  const unsigned short* Ap = a_ws + (size_t)c * NPOS + (size_t)i0 * NDIM;
  const unsigned short* Bp = b_ws + (size_t)c * NPOS + (size_t)j0 * NDIM;

  f32x4 acc[4][4];
#pragma unroll
  for (int mi = 0; mi < 4; ++mi)
#pragma unroll
    for (int ni = 0; ni < 4; ++ni) acc[mi][ni] = (f32x4){0.f, 0.f, 0.f, 0.f};

  const int srow8  = t >> 3;  // row within a 32-row staging group
  const int schunk = t & 7;   // physical 16B chunk within row
  const int mrow = wm * 64 + (lane & 15);
  const int nrow = wn * 64 + (lane & 15);

  for (int kk = 0; kk < 8; ++kk) {
    const int k0 = kk * 64;  // shorts
#pragma unroll
    for (int i = 0; i < 4; ++i) {
      const int row = i * 32 + srow8;
      const int kcs = schunk ^ (row & 7);  // swizzled source chunk
      __builtin_amdgcn_global_load_lds(
          (const __attribute__((address_space(1))) unsigned int*)(Ap + (size_t)row * NDIM + k0 + kcs * 8),
          (__attribute__((address_space(3))) unsigned int*)&sA[(i * 256 + t) * 8], 16, 0, 0);
      __builtin_amdgcn_global_load_lds(
          (const __attribute__((address_space(1))) unsigned int*)(Bp + (size_t)row * NDIM + k0 + kcs * 8),
          (__attribute__((address_space(3))) unsigned int*)&sB[(i * 256 + t) * 8], 16, 0, 0);
    }
    __syncthreads();

#pragma unroll
    for (int ksub = 0; ksub < 2; ++ksub) {
      const int kc = ksub * 4 + (lane >> 4);  // logical 16B chunk 0..7
      bf16x8 af[4], bfr[4];
#pragma unroll
      for (int mi = 0; mi < 4; ++mi) {
        const int r = mrow + mi * 16;
        af[mi] = *(const bf16x8*)&sA[r * 64 + ((kc ^ (r & 7)) << 3)];
      }
#pragma unroll
      for (int ni = 0; ni < 4; ++ni) {
        const int r = nrow + ni * 16;
        bfr[ni] = *(const bf16x8*)&sB[r * 64 + ((kc ^ (r & 7)) << 3)];
      }
#pragma unroll
      for (int mi = 0; mi < 4; ++mi)
#pragma unroll
        for (int ni = 0; ni < 4; ++ni)
          acc[mi][ni] = __builtin_amdgcn_mfma_f32_16x16x32_bf16(af[mi], bfr[ni], acc[mi][ni], 0, 0, 0);
    }
    __syncthreads();
  }

  float* O = out + (size_t)c * NPOS + (size_t)i0 * NDIM + j0;
#pragma unroll
  for (int mi = 0; mi < 4; ++mi)
#pragma unroll
    for (int r = 0; r < 4; ++r) {
      const int m = wm * 64 + mi * 16 + (lane >> 4) * 4 + r;
#pragma unroll
      for (int ni = 0; ni < 4; ++ni) {
        const int n = wn * 64 + ni * 16 + (lane & 15);
        O[(size_t)m * NDIM + n] = acc[mi][ni][r];
      }
    }
}

// ---------------------------------------------------------------- launcher
extern "C" void kernel_launch(void* const* d_in, const int* in_sizes, int n_in,
                              void* d_out, int out_size, void* d_ws, size_t ws_size,
                              hipStream_t stream) {
  const float* z    = (const float*)d_in[0];
  const float* mask = (const float*)d_in[1];
  const float* wag  = (const float*)d_in[2];
  const float* bag  = (const float*)d_in[3];
  const float* wap  = (const float*)d_in[4];
  const float* bap  = (const float*)d_in[5];
  const float* wbg  = (const float*)d_in[6];
  const float* bbg  = (const float*)d_in[7];
  const float* wbp  = (const float*)d_in[8];
  const float* bbp  = (const float*)d_in[9];
  float* out = (float*)d_out;

  unsigned short* wbf  = (unsigned short*)d_ws;
  unsigned short* a_ws = (unsigned short*)((char*)d_ws + 131072);
  unsigned short* b_ws = (unsigned short*)((char*)d_ws + 131072 + (size_t)CH * NPOS * 2);

  conv_weights<<<dim3(256), dim3(256), 0, stream>>>(wag, wap, wbg, wbp, wbf);
  proj_fuse<<<dim3(NPOS / 32), dim3(256), 0, stream>>>(
      z, mask, wbf, bag, bap, bbg, bbp, a_ws, b_ws);
  tri_gemm<<<dim3(4, 4, CH), dim3(256), 0, stream>>>(a_ws, b_ws, out);
}